// Round 1
// baseline (88.550 us; speedup 1.0000x reference)
//
#include <hip/hip_runtime.h>
#include <stdint.h>

#define H 512
#define W 512
#define B 8
#define TW 32
#define TH 8
#define NBLK ((H / TH) * (W / TW) * B)  // 64 * 16 * 8 = 8192

// Fused kernel: edges via wave-ballot bitmasks, clipped EDT from bitmasks,
// softmax/CE/dice/argmax stats, block reduction -> per-block partials (no atomics).
__global__ __launch_bounds__(256) void seg_main(const float* __restrict__ preds,
                                                const int* __restrict__ tgt,
                                                float* __restrict__ partials) {
    __shared__ unsigned long long emask[16];  // edge rows: ey = by0-4+r, bit c <-> ex = bx0-4+c
    __shared__ float red[4][8];

    const int lx = threadIdx.x;  // 0..31
    const int ly = threadIdx.y;  // 0..7
    const int tid = ly * TW + lx;
    const int wave = tid >> 6;
    const int lane = tid & 63;

    const int bx0 = blockIdx.x * TW;
    const int by0 = blockIdx.y * TH;
    const int b = blockIdx.z;
    const int blk = blockIdx.x + (W / TW) * (blockIdx.y + (H / TH) * blockIdx.z);

    const int* T = tgt + (size_t)b * H * W;

    // ---- build 16 edge-row bitmasks (cols 0..39 valid), 4 rows per wave ----
    #pragma unroll
    for (int i = 0; i < 4; ++i) {
        int r = wave * 4 + i;
        int ey = by0 - 4 + r;
        int ex = bx0 - 4 + lane;
        bool edge = false;
        if (lane < 40 && ey >= 0 && ey < H && ex >= 0 && ex < W) {
            int t0 = T[ey * W + ex];
            bool e = false;
            if (ey > 0) e = (t0 != T[(ey - 1) * W + ex]);       // dy > 0 (prepend => row 0 false)
            if (!e && ex > 0) e = (t0 != T[ey * W + ex - 1]);   // dx > 0
            edge = e;
        }
        unsigned long long m = __ballot(edge);
        if (lane == 0) emask[r] = m;
    }
    __syncthreads();

    const int gx = bx0 + lx, gy = by0 + ly;
    const int t = T[gy * W + gx];

    // ---- clipped EDT: min over window offsets with oy^2+ox^2 < 25 ----
    int d2min = 25;
    const unsigned int allow[9] = {0x7Cu, 0xFEu, 0x1FFu, 0x1FFu, 0x1FFu, 0x1FFu, 0x1FFu, 0xFEu, 0x7Cu};
    #pragma unroll
    for (int oy = -4; oy <= 4; ++oy) {
        int r = ly + 4 + oy;
        unsigned int bits = (unsigned int)(emask[r] >> lx) & allow[oy + 4];  // bit i <-> ox = i-4
        if (bits) {
            int ax;
            if      (bits & 0x010u) ax = 0;
            else if (bits & 0x028u) ax = 1;
            else if (bits & 0x044u) ax = 2;
            else if (bits & 0x082u) ax = 3;
            else                    ax = 4;
            int d2 = oy * oy + ax * ax;
            d2min = min(d2min, d2);
        }
    }
    float dist = (d2min >= 25) ? 5.0f : sqrtf((float)d2min);
    float wgt = (dist < 5.0f) ? (2.0f - dist * 0.2f) : 1.0f;  // 1 + (BW-1 scale)*(1-dist/5)

    // ---- softmax / CE / dice terms / argmax ----
    const size_t pix = (size_t)gy * W + gx;
    const float* Pb = preds + (size_t)b * 3 * H * W;
    float p0 = Pb[pix];
    float p1 = Pb[pix + (size_t)H * W];
    float p2 = Pb[pix + (size_t)2 * H * W];
    float mx = fmaxf(p0, fmaxf(p1, p2));
    float e0 = __expf(p0 - mx), e1 = __expf(p1 - mx), e2 = __expf(p2 - mx);
    float se = e0 + e1 + e2;
    float lse = mx + __logf(se);
    float pt = (t == 0) ? p0 : ((t == 1) ? p1 : p2);
    float ce = lse - pt;
    float prob1 = e1 / se;

    int cls = 0;
    float best = p0;
    if (p1 > best) { best = p1; cls = 1; }
    if (p2 > best) { cls = 2; }

    bool bm = wgt > 1.5f;
    float v[7];
    v[0] = ce * wgt;                          // weighted CE sum
    v[1] = (t == 1) ? prob1 : 0.0f;           // sum p1*t1
    v[2] = prob1;                             // sum p1
    v[3] = (t == 1) ? 1.0f : 0.0f;            // sum t1
    v[4] = wgt;                               // sum weights
    v[5] = bm ? 1.0f : 0.0f;                  // cnt
    v[6] = (bm && cls == t) ? 1.0f : 0.0f;    // correct

    #pragma unroll
    for (int off = 32; off >= 1; off >>= 1) {
        #pragma unroll
        for (int k = 0; k < 7; ++k) v[k] += __shfl_down(v[k], off, 64);
    }
    if (lane == 0) {
        #pragma unroll
        for (int k = 0; k < 7; ++k) red[wave][k] = v[k];
    }
    __syncthreads();
    if (tid == 0) {
        #pragma unroll
        for (int k = 0; k < 7; ++k) {
            float s = red[0][k] + red[1][k] + red[2][k] + red[3][k];
            partials[k * NBLK + blk] = s;
        }
    }
}

__global__ __launch_bounds__(256) void seg_final(const float* __restrict__ partials,
                                                 float* __restrict__ out) {
    __shared__ double red[4][8];
    const int tid = threadIdx.x;
    const int wave = tid >> 6, lane = tid & 63;
    double s[7];
    #pragma unroll
    for (int k = 0; k < 7; ++k) {
        double acc = 0.0;
        for (int i = tid; i < NBLK; i += 256) acc += (double)partials[k * NBLK + i];
        s[k] = acc;
    }
    #pragma unroll
    for (int off = 32; off >= 1; off >>= 1) {
        #pragma unroll
        for (int k = 0; k < 7; ++k) s[k] += __shfl_down(s[k], off, 64);
    }
    if (lane == 0) {
        #pragma unroll
        for (int k = 0; k < 7; ++k) red[wave][k] = s[k];
    }
    __syncthreads();
    if (tid == 0) {
        double f[7];
        #pragma unroll
        for (int k = 0; k < 7; ++k) f[k] = red[0][k] + red[1][k] + red[2][k] + red[3][k];
        const double N = (double)B * H * W;
        double wce = f[0] / N;
        double dice = (2.0 * f[1] + 1.0) / (f[2] + f[3] + 1.0);
        double dl = 1.0 - dice;
        double bacc = (f[5] > 0.0) ? (f[6] / f[5]) : 0.0;
        double aw = f[4] / N;
        out[0] = (float)(wce + dl);
        out[1] = (float)wce;
        out[2] = (float)dl;
        out[3] = (float)bacc;
        out[4] = (float)aw;
    }
}

extern "C" void kernel_launch(void* const* d_in, const int* in_sizes, int n_in,
                              void* d_out, int out_size, void* d_ws, size_t ws_size,
                              hipStream_t stream) {
    const float* preds = (const float*)d_in[0];
    const int* tgt = (const int*)d_in[1];
    float* partials = (float*)d_ws;  // needs 7 * 8192 * 4 = 229,376 bytes

    dim3 grid(W / TW, H / TH, B);
    dim3 block(TW, TH);
    seg_main<<<grid, block, 0, stream>>>(preds, tgt, partials);
    seg_final<<<1, 256, 0, stream>>>(partials, (float*)d_out);
}

// Round 2
// 28.544 us; speedup vs baseline: 3.1023x; 3.1023x over previous
//
#include <hip/hip_runtime.h>
#include <stdint.h>

#define H 512
#define W 512
#define B 8
#define TW 32
#define TILEH 32
#define NBX (W / TW)          // 16
#define NBY (H / TILEH)       // 16
#define NBLK (NBX * NBY * B)  // 2048

// Fused kernel: edges via wave-ballot bitmasks (40-row window), clipped EDT from
// bitmasks, softmax/CE/dice/argmax stats for 4 pixels/thread, ballot-popc for
// indicator sums, block reduction -> 7 per-block partials (no atomics).
__global__ __launch_bounds__(256) void seg_main(const float* __restrict__ preds,
                                                const int* __restrict__ tgt,
                                                float* __restrict__ partials) {
    __shared__ unsigned long long emask[40];  // rows by0-4 .. by0+35; bit c <-> ex = bx0-4+c
    __shared__ float redf[4][4];
    __shared__ int redi[4][3];

    const int lx = threadIdx.x;  // 0..31
    const int ly = threadIdx.y;  // 0..7
    const int tid = ly * TW + lx;
    const int wave = tid >> 6;
    const int lane = tid & 63;

    const int bx0 = blockIdx.x * TW;
    const int by0 = blockIdx.y * TILEH;
    const int b = blockIdx.z;
    const int blk = blockIdx.x + NBX * (blockIdx.y + NBY * blockIdx.z);

    const int* T = tgt + (size_t)b * H * W;

    // ---- build 40 edge-row bitmasks, 10 consecutive rows per wave ----
    {
        const int ex = bx0 - 4 + lane;
        const bool xok = (lane < 40) & (ex >= 0) & (ex < W);
        const int r0 = wave * 10;
        int ey = by0 - 4 + r0;
        int tup = 0;
        if (xok && (ey - 1) >= 0 && (ey - 1) < H) tup = T[(ey - 1) * W + ex];
        #pragma unroll
        for (int i = 0; i < 10; ++i, ++ey) {
            const bool rok = xok & (ey >= 0) & (ey < H);
            int t0 = rok ? T[ey * W + ex] : 0;
            int tl = __shfl_up(t0, 1, 64);
            if (lane == 0) tl = (rok & (ex > 0)) ? T[ey * W + ex - 1] : t0;
            // edge = differs from up neighbor (row>0) OR left neighbor (col>0)
            bool e = rok & ((((ey > 0) & (t0 != tup))) | (((ex > 0) & (t0 != tl))));
            unsigned long long m = __ballot(e);
            if (lane == 0) emask[r0 + i] = m;
            tup = t0;  // valid whenever next row is in-image and ey>0 there
        }
    }
    __syncthreads();

    const float* Pb = preds + (size_t)b * 3 * H * W;
    const unsigned int allow[9] = {0x7Cu, 0xFEu, 0x1FFu, 0x1FFu, 0x1FFu,
                                   0x1FFu, 0x1FFu, 0xFEu, 0x7Cu};

    float s0 = 0.f, s1 = 0.f, s2 = 0.f, s3 = 0.f;  // ce*w, p1*t1, p1, w
    int c_t1 = 0, c_bm = 0, c_ok = 0;              // via ballot popcount (wave totals)

    #pragma unroll
    for (int j = 0; j < 4; ++j) {
        const int py = ly + j * 8;           // 0..31 within tile
        const int gy = by0 + py;
        const int gx = bx0 + lx;
        const int t = T[gy * W + gx];

        // ---- clipped EDT over offsets with oy^2+ox^2 < 25 ----
        int d2min = 25;
        #pragma unroll
        for (int oy = -4; oy <= 4; ++oy) {
            unsigned int bits = (unsigned int)(emask[py + 4 + oy] >> lx) & allow[oy + 4];
            if (bits) {
                int ax;
                if      (bits & 0x010u) ax = 0;
                else if (bits & 0x028u) ax = 1;
                else if (bits & 0x044u) ax = 2;
                else if (bits & 0x082u) ax = 3;
                else                    ax = 4;
                d2min = min(d2min, oy * oy + ax * ax);
            }
        }
        float dist = (d2min >= 25) ? 5.0f : sqrtf((float)d2min);
        float wgt = (dist < 5.0f) ? (2.0f - dist * 0.2f) : 1.0f;

        // ---- softmax / CE / dice terms / argmax ----
        const size_t pix = (size_t)gy * W + gx;
        float p0 = Pb[pix];
        float p1 = Pb[pix + (size_t)H * W];
        float p2 = Pb[pix + (size_t)2 * H * W];
        float mx = fmaxf(p0, fmaxf(p1, p2));
        float e0 = __expf(p0 - mx), e1 = __expf(p1 - mx), e2 = __expf(p2 - mx);
        float se = e0 + e1 + e2;
        float lse = mx + __logf(se);
        float pt = (t == 0) ? p0 : ((t == 1) ? p1 : p2);
        float ce = lse - pt;
        float prob1 = e1 / se;

        int cls = 0;
        float best = p0;
        if (p1 > best) { best = p1; cls = 1; }
        if (p2 > best) { cls = 2; }

        bool bm = wgt > 1.5f;
        bool ok = bm & (cls == t);
        c_t1 += __popcll(__ballot(t == 1));
        c_bm += __popcll(__ballot(bm));
        c_ok += __popcll(__ballot(ok));

        s0 += ce * wgt;
        s1 += (t == 1) ? prob1 : 0.0f;
        s2 += prob1;
        s3 += wgt;
    }

    // ---- wave butterfly on the 4 float accumulators ----
    #pragma unroll
    for (int off = 32; off >= 1; off >>= 1) {
        s0 += __shfl_down(s0, off, 64);
        s1 += __shfl_down(s1, off, 64);
        s2 += __shfl_down(s2, off, 64);
        s3 += __shfl_down(s3, off, 64);
    }
    if (lane == 0) {
        redf[wave][0] = s0; redf[wave][1] = s1; redf[wave][2] = s2; redf[wave][3] = s3;
        redi[wave][0] = c_t1; redi[wave][1] = c_bm; redi[wave][2] = c_ok;
    }
    __syncthreads();
    if (tid == 0) {
        float f0 = redf[0][0] + redf[1][0] + redf[2][0] + redf[3][0];
        float f1 = redf[0][1] + redf[1][1] + redf[2][1] + redf[3][1];
        float f2 = redf[0][2] + redf[1][2] + redf[2][2] + redf[3][2];
        float f3 = redf[0][3] + redf[1][3] + redf[2][3] + redf[3][3];
        int i0 = redi[0][0] + redi[1][0] + redi[2][0] + redi[3][0];
        int i1 = redi[0][1] + redi[1][1] + redi[2][1] + redi[3][1];
        int i2 = redi[0][2] + redi[1][2] + redi[2][2] + redi[3][2];
        partials[0 * NBLK + blk] = f0;          // sum ce*w
        partials[1 * NBLK + blk] = f1;          // sum p1*t1
        partials[2 * NBLK + blk] = f2;          // sum p1
        partials[3 * NBLK + blk] = (float)i0;   // sum t1
        partials[4 * NBLK + blk] = f3;          // sum w
        partials[5 * NBLK + blk] = (float)i1;   // cnt
        partials[6 * NBLK + blk] = (float)i2;   // correct
    }
}

__global__ __launch_bounds__(256) void seg_final(const float* __restrict__ partials,
                                                 float* __restrict__ out) {
    __shared__ double red[4][7];
    const int tid = threadIdx.x;
    const int wave = tid >> 6, lane = tid & 63;

    // 2048 floats per quantity = 512 float4; 256 threads x 2 float4 each.
    const float4* p4 = (const float4*)partials;
    float4 va[7], vb[7];
    #pragma unroll
    for (int k = 0; k < 7; ++k) {
        va[k] = p4[k * 512 + tid];
        vb[k] = p4[k * 512 + 256 + tid];
    }
    double s[7];
    #pragma unroll
    for (int k = 0; k < 7; ++k)
        s[k] = (((double)va[k].x + va[k].y) + ((double)va[k].z + va[k].w)) +
               (((double)vb[k].x + vb[k].y) + ((double)vb[k].z + vb[k].w));

    #pragma unroll
    for (int off = 32; off >= 1; off >>= 1) {
        #pragma unroll
        for (int k = 0; k < 7; ++k) s[k] += __shfl_down(s[k], off, 64);
    }
    if (lane == 0) {
        #pragma unroll
        for (int k = 0; k < 7; ++k) red[wave][k] = s[k];
    }
    __syncthreads();
    if (tid == 0) {
        double f[7];
        #pragma unroll
        for (int k = 0; k < 7; ++k)
            f[k] = red[0][k] + red[1][k] + red[2][k] + red[3][k];
        const double N = (double)B * H * W;
        double wce = f[0] / N;
        double dice = (2.0 * f[1] + 1.0) / (f[2] + f[3] + 1.0);
        double dl = 1.0 - dice;
        double bacc = (f[5] > 0.0) ? (f[6] / f[5]) : 0.0;
        double aw = f[4] / N;
        out[0] = (float)(wce + dl);
        out[1] = (float)wce;
        out[2] = (float)dl;
        out[3] = (float)bacc;
        out[4] = (float)aw;
    }
}

extern "C" void kernel_launch(void* const* d_in, const int* in_sizes, int n_in,
                              void* d_out, int out_size, void* d_ws, size_t ws_size,
                              hipStream_t stream) {
    const float* preds = (const float*)d_in[0];
    const int* tgt = (const int*)d_in[1];
    float* partials = (float*)d_ws;  // needs 7 * 2048 * 4 = 57,344 bytes

    dim3 grid(NBX, NBY, B);
    dim3 block(TW, 8);
    seg_main<<<grid, block, 0, stream>>>(preds, tgt, partials);
    seg_final<<<1, 256, 0, stream>>>(partials, (float*)d_out);
}